// Round 4
// baseline (1440.370 us; speedup 1.0000x reference)
//
#include <hip/hip_runtime.h>
#include <math.h>

#define B_   2
#define T_   1024
#define DM_  1024
#define D_   2048
#define N_   16
#define DTR_ 128
#define NDBC 160           // DTR + 2N
#define ROWS (B_*T_)       // 2048
#define EPS_ 1e-6f

// ---------------- 1. RMS scale: x (fp32) -> scale[row] (fp32) ----------------
__global__ __launch_bounds__(256) void rms_scale_kernel(const float* __restrict__ x,
                                                        float* __restrict__ scale)
{
    const int row = blockIdx.x;              // 0..2047
    const float* xr = x + (size_t)row * DM_;
    const int tid = threadIdx.x;
    float ss = 0.f;
#pragma unroll
    for (int i = 0; i < 4; ++i) {
        float v = xr[tid + i*256];
        ss += v*v;
    }
#pragma unroll
    for (int off = 32; off >= 1; off >>= 1) ss += __shfl_xor(ss, off, 64);
    __shared__ float red[4];
    if ((tid & 63) == 0) red[tid >> 6] = ss;
    __syncthreads();
    if (tid == 0) {
        float tot = red[0] + red[1] + red[2] + red[3];
        scale[row] = rsqrtf(tot / (float)DM_ + EPS_);
    }
}

// ------- generic GEMM: C[M,N] = A[M,K] * Bw[K,N] + bias (all fp32) ----------
// AMODE 0: A = Afp with stride lda. AMODE 1: A = x with fused rmsnorm (x*scale*w).
// EPI 0: store. EPI 1: softplus then store. EPI 2: +resid then store.
template<int EPI, int AMODE>
__global__ __launch_bounds__(256) void gemm_kernel(
    const float* __restrict__ Afp, int lda,
    const float* __restrict__ scaleBuf,
    const float* __restrict__ rmsw,
    const float* __restrict__ Bw,
    const float* __restrict__ bias,
    float*       __restrict__ Cf,
    const float* __restrict__ resid,
    int M, int N, int Kd)
{
    constexpr int BM = 64, BN = 64, BK = 16;
    __shared__ float As[BK][BM+4];   // stride 68 floats = 272 B (16B multiple)
    __shared__ float Bs[BK][BN+4];
    const int bm = blockIdx.y * BM;
    const int bn = blockIdx.x * BN;
    const int tid = threadIdx.x;
    const int ty = tid >> 4, tx = tid & 15;        // 16x16 threads, 4x4 micro-tile
    const int mA = tid >> 2, kq = tid & 3;         // A tile: 64 rows x 4x(4k)
    const int kB = tid >> 4, nB = (tid & 15) << 2; // B tile: 16 k-rows x 64 cols

    float acc[4][4] = {};
    float sc = 1.f;
    if constexpr (AMODE == 1) sc = scaleBuf[bm + mA];

    for (int k0 = 0; k0 < Kd; k0 += BK) {
        float4 av = *(const float4*)(Afp + (size_t)(bm + mA) * lda + k0 + (kq << 2));
        if constexpr (AMODE == 1) {
            float4 wx = *(const float4*)(rmsw + k0 + (kq << 2));
            av.x *= wx.x * sc;
            av.y *= wx.y * sc;
            av.z *= wx.z * sc;
            av.w *= wx.w * sc;
        }
        float4 bvf;
        if (bn + nB < N) {
            bvf = *(const float4*)(Bw + (size_t)(k0 + kB) * N + bn + nB);
        } else {
            bvf = make_float4(0.f, 0.f, 0.f, 0.f);
        }
        __syncthreads();   // prior iteration's LDS reads complete
        As[(kq<<2)+0][mA] = av.x;
        As[(kq<<2)+1][mA] = av.y;
        As[(kq<<2)+2][mA] = av.z;
        As[(kq<<2)+3][mA] = av.w;
        *(float4*)&Bs[kB][nB] = bvf;
        __syncthreads();
#pragma unroll
        for (int kk = 0; kk < BK; ++kk) {
            float4 a4 = *(const float4*)&As[kk][ty << 2];
            float4 b4 = *(const float4*)&Bs[kk][tx << 2];
            float ar[4] = {a4.x, a4.y, a4.z, a4.w};
            float br[4] = {b4.x, b4.y, b4.z, b4.w};
#pragma unroll
            for (int i = 0; i < 4; ++i)
#pragma unroll
                for (int j = 0; j < 4; ++j)
                    acc[i][j] = fmaf(ar[i], br[j], acc[i][j]);
        }
    }

#pragma unroll
    for (int i = 0; i < 4; ++i) {
        int row = bm + (ty << 2) + i;
#pragma unroll
        for (int j = 0; j < 4; ++j) {
            int col = bn + (tx << 2) + j;
            if (col < N) {
                float v = acc[i][j] + bias[col];
                if constexpr (EPI == 1) {
                    v = fmaxf(v, 0.f) + log1pf(expf(-fabsf(v)));   // stable softplus
                }
                if constexpr (EPI == 2) {
                    v += resid[(size_t)row * N + col];
                }
                Cf[(size_t)row * N + col] = v;
            }
        }
    }
}

// ---------------- 3. depthwise causal conv (K=4) + SiLU -------------------
// x1-preconv lives in proj[..., :D]; proj row stride 2*D. Writes x1c [ROWS,D].
__global__ __launch_bounds__(256) void conv_silu_kernel(
    const float* __restrict__ proj,
    const float* __restrict__ cw,
    const float* __restrict__ cb,
    float*       __restrict__ x1c)
{
    int idx = blockIdx.x * 256 + threadIdx.x;   // over ROWS*D
    int d   = idx & (D_ - 1);
    int row = idx >> 11;                        // b*T + t
    int t   = row & (T_ - 1);
    const float* base = proj + (size_t)row * (2*D_) + d;
    float acc = cb[d];
    float w0 = cw[d*4+0];
    float w1 = cw[d*4+1];
    float w2 = cw[d*4+2];
    float w3 = cw[d*4+3];
    acc = fmaf(w3, base[0], acc);
    if (t >= 1) acc = fmaf(w2, base[-(2*D_)],   acc);
    if (t >= 2) acc = fmaf(w1, base[-2*(2*D_)], acc);
    if (t >= 3) acc = fmaf(w0, base[-3*(2*D_)], acc);
    float sg = 1.f / (1.f + expf(-acc));
    x1c[idx] = acc * sg;
}

// ---------------- 6+7. selective scan, fused gate --------------------------
// lane n of each 16-lane group holds state h[n] for one (b,d) channel.
// Writes y*silu(g) into proj[..., :D] (x1-preconv slots, dead after conv).
__global__ __launch_bounds__(256) void scan_kernel(
    const float* __restrict__ delta,
    const float* __restrict__ x1c,
    const float* __restrict__ dbc,    // [..., 128:144]=Bm  [..., 144:160]=Cm
    const float* __restrict__ A_log,
    float*       __restrict__ proj)   // g at col D+d (read), y at col d (write)
{
    int tid  = blockIdx.x * 256 + threadIdx.x;
    int n    = tid & 15;
    int bd   = tid >> 4;           // 0..4095
    int b    = bd >> 11;
    int d    = bd & (D_ - 1);
    float a_coef = -expf(A_log[d * N_ + n]);
    float hstate = 0.f;
    size_t rowbase = (size_t)b * T_;
    for (int t = 0; t < T_; ++t) {
        size_t r = rowbase + t;
        float dv = delta[r * D_ + d];
        float xv = x1c [r * D_ + d];
        float Bv = dbc[r * NDBC + DTR_ + n];
        float Cv = dbc[r * NDBC + DTR_ + N_ + n];
        float a = expf(dv * a_coef);
        hstate = fmaf(a, hstate, dv * Bv * xv);
        float part = hstate * Cv;
        part += __shfl_xor(part, 1, 16);
        part += __shfl_xor(part, 2, 16);
        part += __shfl_xor(part, 4, 16);
        part += __shfl_xor(part, 8, 16);
        if (n == 0) {
            float g = proj[r * (2*D_) + D_ + d];
            float sg = 1.f / (1.f + expf(-g));
            proj[r * (2*D_) + d] = part * g * sg;
        }
    }
}

extern "C" void kernel_launch(void* const* d_in, const int* in_sizes, int n_in,
                              void* d_out, int out_size, void* d_ws, size_t ws_size,
                              hipStream_t stream)
{
    const float* x      = (const float*)d_in[0];
    const float* rms_w  = (const float*)d_in[1];
    const float* in_W   = (const float*)d_in[2];
    const float* in_b   = (const float*)d_in[3];
    const float* conv_w = (const float*)d_in[4];
    const float* conv_b = (const float*)d_in[5];
    const float* A_log  = (const float*)d_in[6];
    const float* dbc_W  = (const float*)d_in[7];
    const float* dbc_b  = (const float*)d_in[8];
    const float* dup_W  = (const float*)d_in[9];
    const float* dup_b  = (const float*)d_in[10];
    const float* out_W  = (const float*)d_in[11];
    const float* out_b  = (const float*)d_in[12];
    float* out = (float*)d_out;    // fp32 output, per reference dtype

    float* ws    = (float*)d_ws;
    float* proj  = ws;                           // ROWS*2D  = 8M  f (32 MB)
    float* x1c   = proj  + (size_t)ROWS*2*D_;    // ROWS*D   = 4M  f (16 MB)
    float* dbc   = x1c   + (size_t)ROWS*D_;      // ROWS*160 = 320K f
    float* delta = dbc   + (size_t)ROWS*NDBC;    // ROWS*D   = 4M  f (16 MB)
    float* scale = delta + (size_t)ROWS*D_;      // ROWS     = 2K  f
    // total ~65.3 MiB of d_ws

    // 1. RMS scale per row
    rms_scale_kernel<<<ROWS, 256, 0, stream>>>(x, scale);
    // 2. in_proj (fused rmsnorm): proj = (x*scale*rms_w) @ in_W + in_b   [2048 x 4096], K=1024
    gemm_kernel<0,1><<<dim3((2*D_)/64, ROWS/64), 256, 0, stream>>>(
        x, DM_, scale, rms_w, in_W, in_b, proj, nullptr, ROWS, 2*D_, DM_);
    // 3. causal depthwise conv + silu -> x1c
    conv_silu_kernel<<<(ROWS*D_)/256, 256, 0, stream>>>(proj, conv_w, conv_b, x1c);
    // 4. dbc = x1c @ dbc_W + dbc_b                [2048 x 160], K=2048
    gemm_kernel<0,0><<<dim3(3, ROWS/64), 256, 0, stream>>>(
        x1c, D_, nullptr, nullptr, dbc_W, dbc_b, dbc, nullptr, ROWS, NDBC, D_);
    // 5. delta = softplus(dbc[:, :128] @ dup_W + dup_b)   [2048 x 2048], K=128
    gemm_kernel<1,0><<<dim3(D_/64, ROWS/64), 256, 0, stream>>>(
        dbc, NDBC, nullptr, nullptr, dup_W, dup_b, delta, nullptr, ROWS, D_, DTR_);
    // 6+7. selective scan + gate -> y stored into proj[:, :D]
    scan_kernel<<<(B_*D_*N_)/256, 256, 0, stream>>>(delta, x1c, dbc, A_log, proj);
    // 8. out = y @ out_W + out_b + residual (fp32 store)   [2048 x 1024], K=2048
    gemm_kernel<2,0><<<dim3(DM_/64, ROWS/64), 256, 0, stream>>>(
        proj, 2*D_, nullptr, nullptr, out_W, out_b, out, x, ROWS, DM_, D_);
}

// Round 5
// 804.744 us; speedup vs baseline: 1.7898x; 1.7898x over previous
//
#include <hip/hip_runtime.h>
#include <math.h>

#define B_   2
#define T_   1024
#define DM_  1024
#define D_   2048
#define N_   16
#define DTR_ 128
#define NDBC 160           // DTR + 2N
#define ROWS (B_*T_)       // 2048
#define EPS_ 1e-6f
#define NCH  16            // scan chunks per channel
#define CLEN (T_/NCH)      // 64 steps per chunk

// ---------------- 1. RMS scale: x (fp32) -> scale[row] (fp32) ----------------
__global__ __launch_bounds__(256) void rms_scale_kernel(const float* __restrict__ x,
                                                        float* __restrict__ scale)
{
    const int row = blockIdx.x;              // 0..2047
    const float* xr = x + (size_t)row * DM_;
    const int tid = threadIdx.x;
    float ss = 0.f;
#pragma unroll
    for (int i = 0; i < 4; ++i) {
        float v = xr[tid + i*256];
        ss += v*v;
    }
#pragma unroll
    for (int off = 32; off >= 1; off >>= 1) ss += __shfl_xor(ss, off, 64);
    __shared__ float red[4];
    if ((tid & 63) == 0) red[tid >> 6] = ss;
    __syncthreads();
    if (tid == 0) {
        float tot = red[0] + red[1] + red[2] + red[3];
        scale[row] = rsqrtf(tot / (float)DM_ + EPS_);
    }
}

// ------- generic GEMM: C[M,N] = A[M,K] * Bw[K,N] + bias (all fp32) ----------
// AMODE 0: A = Afp with stride lda. AMODE 1: A = x with fused rmsnorm (x*scale*w).
// EPI 0: store. EPI 1: softplus then store. EPI 2: +resid then store.
template<int EPI, int AMODE>
__global__ __launch_bounds__(256) void gemm_kernel(
    const float* __restrict__ Afp, int lda,
    const float* __restrict__ scaleBuf,
    const float* __restrict__ rmsw,
    const float* __restrict__ Bw,
    const float* __restrict__ bias,
    float*       __restrict__ Cf,
    const float* __restrict__ resid,
    int M, int N, int Kd)
{
    constexpr int BM = 64, BN = 64, BK = 16;
    __shared__ float As[BK][BM+4];   // stride 68 floats = 272 B (16B multiple)
    __shared__ float Bs[BK][BN+4];
    const int bm = blockIdx.y * BM;
    const int bn = blockIdx.x * BN;
    const int tid = threadIdx.x;
    const int ty = tid >> 4, tx = tid & 15;        // 16x16 threads, 4x4 micro-tile
    const int mA = tid >> 2, kq = tid & 3;         // A tile: 64 rows x 4x(4k)
    const int kB = tid >> 4, nB = (tid & 15) << 2; // B tile: 16 k-rows x 64 cols

    float acc[4][4] = {};
    float sc = 1.f;
    if constexpr (AMODE == 1) sc = scaleBuf[bm + mA];

    for (int k0 = 0; k0 < Kd; k0 += BK) {
        float4 av = *(const float4*)(Afp + (size_t)(bm + mA) * lda + k0 + (kq << 2));
        if constexpr (AMODE == 1) {
            float4 wx = *(const float4*)(rmsw + k0 + (kq << 2));
            av.x *= wx.x * sc;
            av.y *= wx.y * sc;
            av.z *= wx.z * sc;
            av.w *= wx.w * sc;
        }
        float4 bvf;
        if (bn + nB < N) {
            bvf = *(const float4*)(Bw + (size_t)(k0 + kB) * N + bn + nB);
        } else {
            bvf = make_float4(0.f, 0.f, 0.f, 0.f);
        }
        __syncthreads();   // prior iteration's LDS reads complete
        As[(kq<<2)+0][mA] = av.x;
        As[(kq<<2)+1][mA] = av.y;
        As[(kq<<2)+2][mA] = av.z;
        As[(kq<<2)+3][mA] = av.w;
        *(float4*)&Bs[kB][nB] = bvf;
        __syncthreads();
#pragma unroll
        for (int kk = 0; kk < BK; ++kk) {
            float4 a4 = *(const float4*)&As[kk][ty << 2];
            float4 b4 = *(const float4*)&Bs[kk][tx << 2];
            float ar[4] = {a4.x, a4.y, a4.z, a4.w};
            float br[4] = {b4.x, b4.y, b4.z, b4.w};
#pragma unroll
            for (int i = 0; i < 4; ++i)
#pragma unroll
                for (int j = 0; j < 4; ++j)
                    acc[i][j] = fmaf(ar[i], br[j], acc[i][j]);
        }
    }

#pragma unroll
    for (int i = 0; i < 4; ++i) {
        int row = bm + (ty << 2) + i;
#pragma unroll
        for (int j = 0; j < 4; ++j) {
            int col = bn + (tx << 2) + j;
            if (col < N) {
                float v = acc[i][j] + bias[col];
                if constexpr (EPI == 1) {
                    v = fmaxf(v, 0.f) + log1pf(expf(-fabsf(v)));   // stable softplus
                }
                if constexpr (EPI == 2) {
                    v += resid[(size_t)row * N + col];
                }
                Cf[(size_t)row * N + col] = v;
            }
        }
    }
}

// ---------------- 3. depthwise causal conv (K=4) + SiLU -------------------
// x1-preconv lives in proj[..., :D]; proj row stride 2*D. Writes x1c [ROWS,D].
__global__ __launch_bounds__(256) void conv_silu_kernel(
    const float* __restrict__ proj,
    const float* __restrict__ cw,
    const float* __restrict__ cb,
    float*       __restrict__ x1c)
{
    int idx = blockIdx.x * 256 + threadIdx.x;   // over ROWS*D
    int d   = idx & (D_ - 1);
    int row = idx >> 11;                        // b*T + t
    int t   = row & (T_ - 1);
    const float* base = proj + (size_t)row * (2*D_) + d;
    float acc = cb[d];
    float w0 = cw[d*4+0];
    float w1 = cw[d*4+1];
    float w2 = cw[d*4+2];
    float w3 = cw[d*4+3];
    acc = fmaf(w3, base[0], acc);
    if (t >= 1) acc = fmaf(w2, base[-(2*D_)],   acc);
    if (t >= 2) acc = fmaf(w1, base[-2*(2*D_)], acc);
    if (t >= 3) acc = fmaf(w0, base[-3*(2*D_)], acc);
    float sg = 1.f / (1.f + expf(-acc));
    x1c[idx] = acc * sg;
}

// ------- 6+7. chunked selective scan + gate, one block per (b,d) channel -----
// 256 threads = NCH(16) chunks x N(16) states. Linear recurrence h<-a*h+b is
// split into per-chunk local scans (P=decay product, S=local state), a cheap
// LDS chunk-prefix, then a re-scan with the true h0 fused with the C-
// contraction (16-lane shfl) and the SiLU gate. y overwrites proj[:, :D].
__global__ __launch_bounds__(256) void scan_block_kernel(
    const float* __restrict__ delta,
    const float* __restrict__ x1c,
    const float* __restrict__ dbc,    // [..., 128:144]=Bm  [..., 144:160]=Cm
    const float* __restrict__ A_log,
    float*       __restrict__ proj)   // g at col D+d (read), y at col d (write)
{
    __shared__ float dvs[T_ + NCH];   // swizzled index f(t)=t+(t>>6): groups in a
    __shared__ float xvs[T_ + NCH];   // wave hit distinct banks (65c+j mod 32)
    __shared__ float gs [T_ + NCH];
    __shared__ float Pl[NCH][N_];
    __shared__ float Sl[NCH][N_];

    const int tid = threadIdx.x;
    const int d = blockIdx.x & (D_ - 1);
    const int b = blockIdx.x >> 11;
    const int n = tid & 15;
    const int c = tid >> 4;
    const size_t rb = (size_t)b * T_;

    // phase 0: stage this channel's time series into LDS
    for (int i = tid; i < T_; i += 256) {
        int fi = i + (i >> 6);
        dvs[fi] = delta[(rb + i) * D_ + d];
        xvs[fi] = x1c [(rb + i) * D_ + d];
        gs [fi] = proj[(rb + i) * (2*D_) + D_ + d];
    }
    const float a_coef = -expf(A_log[d * N_ + n]);
    __syncthreads();

    // phase 1: local chunk scan from h=0
    float P = 1.f, S = 0.f;
    const int t0 = c * CLEN;
    for (int j = 0; j < CLEN; ++j) {
        int t = t0 + j;
        int ft = t + (t >> 6);
        float dv = dvs[ft];
        float xv = xvs[ft];
        float Bv = dbc[(rb + t) * NDBC + DTR_ + n];
        float a = expf(dv * a_coef);
        P *= a;
        S = fmaf(a, S, dv * Bv * xv);
    }
    Pl[c][n] = P;
    Sl[c][n] = S;
    __syncthreads();

    // phase 2: chunk prefix combine (redundant per thread, <=15 steps)
    float h = 0.f;
    for (int c2 = 0; c2 < c; ++c2)
        h = fmaf(Pl[c2][n], h, Sl[c2][n]);

    // phase 3: re-scan with true h0; C-contraction + gate + store
    for (int j = 0; j < CLEN; ++j) {
        int t = t0 + j;
        int ft = t + (t >> 6);
        float dv = dvs[ft];
        float xv = xvs[ft];
        size_t r = rb + t;
        float Bv = dbc[r * NDBC + DTR_ + n];
        float Cv = dbc[r * NDBC + DTR_ + N_ + n];
        float a = expf(dv * a_coef);
        h = fmaf(a, h, dv * Bv * xv);
        float part = h * Cv;
        part += __shfl_xor(part, 1, 16);
        part += __shfl_xor(part, 2, 16);
        part += __shfl_xor(part, 4, 16);
        part += __shfl_xor(part, 8, 16);
        if (n == 0) {
            float g = gs[ft];
            float sg = 1.f / (1.f + expf(-g));
            proj[r * (2*D_) + d] = part * g * sg;
        }
    }
}

extern "C" void kernel_launch(void* const* d_in, const int* in_sizes, int n_in,
                              void* d_out, int out_size, void* d_ws, size_t ws_size,
                              hipStream_t stream)
{
    const float* x      = (const float*)d_in[0];
    const float* rms_w  = (const float*)d_in[1];
    const float* in_W   = (const float*)d_in[2];
    const float* in_b   = (const float*)d_in[3];
    const float* conv_w = (const float*)d_in[4];
    const float* conv_b = (const float*)d_in[5];
    const float* A_log  = (const float*)d_in[6];
    const float* dbc_W  = (const float*)d_in[7];
    const float* dbc_b  = (const float*)d_in[8];
    const float* dup_W  = (const float*)d_in[9];
    const float* dup_b  = (const float*)d_in[10];
    const float* out_W  = (const float*)d_in[11];
    const float* out_b  = (const float*)d_in[12];
    float* out = (float*)d_out;    // fp32 output, per reference dtype

    float* ws    = (float*)d_ws;
    float* proj  = ws;                           // ROWS*2D  = 8M  f (32 MB)
    float* x1c   = proj  + (size_t)ROWS*2*D_;    // ROWS*D   = 4M  f (16 MB)
    float* dbc   = x1c   + (size_t)ROWS*D_;      // ROWS*160 = 320K f
    float* delta = dbc   + (size_t)ROWS*NDBC;    // ROWS*D   = 4M  f (16 MB)
    float* scale = delta + (size_t)ROWS*D_;      // ROWS     = 2K  f
    // total ~65.3 MiB of d_ws

    // 1. RMS scale per row
    rms_scale_kernel<<<ROWS, 256, 0, stream>>>(x, scale);
    // 2. in_proj (fused rmsnorm): proj = (x*scale*rms_w) @ in_W + in_b   [2048 x 4096], K=1024
    gemm_kernel<0,1><<<dim3((2*D_)/64, ROWS/64), 256, 0, stream>>>(
        x, DM_, scale, rms_w, in_W, in_b, proj, nullptr, ROWS, 2*D_, DM_);
    // 3. causal depthwise conv + silu -> x1c
    conv_silu_kernel<<<(ROWS*D_)/256, 256, 0, stream>>>(proj, conv_w, conv_b, x1c);
    // 4. dbc = x1c @ dbc_W + dbc_b                [2048 x 160], K=2048
    gemm_kernel<0,0><<<dim3(3, ROWS/64), 256, 0, stream>>>(
        x1c, D_, nullptr, nullptr, dbc_W, dbc_b, dbc, nullptr, ROWS, NDBC, D_);
    // 5. delta = softplus(dbc[:, :128] @ dup_W + dup_b)   [2048 x 2048], K=128
    gemm_kernel<1,0><<<dim3(D_/64, ROWS/64), 256, 0, stream>>>(
        dbc, NDBC, nullptr, nullptr, dup_W, dup_b, delta, nullptr, ROWS, D_, DTR_);
    // 6+7. chunked selective scan + gate -> y stored into proj[:, :D]
    scan_block_kernel<<<B_*D_, 256, 0, stream>>>(delta, x1c, dbc, A_log, proj);
    // 8. out = y @ out_W + out_b + residual (fp32 store)   [2048 x 1024], K=2048
    gemm_kernel<2,0><<<dim3(DM_/64, ROWS/64), 256, 0, stream>>>(
        proj, 2*D_, nullptr, nullptr, out_W, out_b, out, x, ROWS, DM_, D_);
}

// Round 6
// 508.830 us; speedup vs baseline: 2.8307x; 1.5816x over previous
//
#include <hip/hip_runtime.h>
#include <math.h>

typedef unsigned short us;
typedef __attribute__((ext_vector_type(8))) short frag8;
typedef __attribute__((ext_vector_type(4))) float f4;

#define B_   2
#define T_   1024
#define DM_  1024
#define D_   2048
#define N_   16
#define DTR_ 128
#define NDBC 160           // DTR + 2N
#define ROWS (B_*T_)       // 2048
#define EPS_ 1e-6f
#define NCH  16            // scan chunks per channel
#define CLEN (T_/NCH)      // 64 steps per chunk

__device__ __forceinline__ float us2f(us s){
    return __uint_as_float(((unsigned int)s) << 16);
}
__device__ __forceinline__ us f2us(float f){   // RTN-even fp32->bf16
    unsigned int u = __float_as_uint(f);
    return (us)((u + 0x7FFF + ((u >> 16) & 1)) >> 16);
}

// ------------- weight prep: transpose fp32 [R][C] -> bf16 [C][R] -------------
__global__ __launch_bounds__(256) void transpose_bf(const float* __restrict__ in,
                                                    us* __restrict__ out, int R, int C)
{
    __shared__ us tile[32][33];
    int c0 = blockIdx.x * 32, r0 = blockIdx.y * 32;
    int tx = threadIdx.x, ty = threadIdx.y;   // 32 x 8
    for (int i = ty; i < 32; i += 8) {
        int r = r0 + i, c = c0 + tx;
        tile[i][tx] = (r < R && c < C) ? f2us(in[(size_t)r * C + c]) : (us)0;
    }
    __syncthreads();
    for (int i = ty; i < 32; i += 8) {
        int c = c0 + i, r = r0 + tx;
        if (c < C && r < R) out[(size_t)c * R + r] = tile[tx][i];
    }
}

// ---------------- RMS scale: x (fp32) -> scale[row] ----------------
__global__ __launch_bounds__(256) void rms_scale_kernel(const float* __restrict__ x,
                                                        float* __restrict__ scale)
{
    const int row = blockIdx.x;
    const float* xr = x + (size_t)row * DM_;
    const int tid = threadIdx.x;
    float ss = 0.f;
#pragma unroll
    for (int i = 0; i < 4; ++i) { float v = xr[tid + i*256]; ss += v*v; }
#pragma unroll
    for (int off = 32; off >= 1; off >>= 1) ss += __shfl_xor(ss, off, 64);
    __shared__ float red[4];
    if ((tid & 63) == 0) red[tid >> 6] = ss;
    __syncthreads();
    if (tid == 0) {
        float tot = red[0] + red[1] + red[2] + red[3];
        scale[row] = rsqrtf(tot / (float)DM_ + EPS_);
    }
}

// ---------------- rmsnorm apply -> bf16 A for in_proj ----------------
__global__ __launch_bounds__(256) void hbf_kernel(const float* __restrict__ x,
                                                  const float* __restrict__ scale,
                                                  const float* __restrict__ rms_w,
                                                  us* __restrict__ hbf)
{
    int idx = blockIdx.x * 256 + threadIdx.x;       // ROWS*DM
    int row = idx >> 10, k = idx & (DM_ - 1);
    hbf[idx] = f2us(x[idx] * scale[row] * rms_w[k]);
}

// ---------- MFMA GEMM: C[M,N] = A[M,K](bf16) * Bt[N,K](bf16)^T + bias --------
// 128x128 tile / block of 4 waves; each wave 64x64 via 4x4 mfma_f32_16x16x32_bf16.
// EPI 0: store fp32. 1: softplus->fp32. 2: +resid->fp32. 3: fp32 + bf16 aux (col<DTR).
template<int EPI>
__global__ __launch_bounds__(256) void mgemm(
    const us*    __restrict__ A,     // [M][K]
    const us*    __restrict__ Bt,    // [N][K]
    const float* __restrict__ bias,  // [N]
    float*       __restrict__ Cf,    // [M][N]
    us*          __restrict__ Caux,  // EPI==3
    const float* __restrict__ resid, // EPI==2
    int M, int N, int K)
{
    __shared__ us As[128][72];   // 72-short rows: frag-read banks (m+q)%8 uniform
    __shared__ us Bs[128][72];
    const int tid = threadIdx.x;
    const int bm = blockIdx.y * 128;
    const int bn = blockIdx.x * 128;
    const int w = tid >> 6, lane = tid & 63;
    const int wr = w >> 1, wc = w & 1;
    const int m16 = lane & 15, quad = lane >> 4;

    f4 acc[4][4];
#pragma unroll
    for (int i = 0; i < 4; ++i)
#pragma unroll
        for (int j = 0; j < 4; ++j)
            acc[i][j] = (f4){0.f, 0.f, 0.f, 0.f};

    for (int k0 = 0; k0 < K; k0 += 64) {
        __syncthreads();   // prior iter's frag reads done before overwrite
#pragma unroll
        for (int i = 0; i < 4; ++i) {
            int chunk = i * 256 + tid;           // 1024 chunks of 16B
            int row = chunk >> 3, c8 = (chunk & 7) * 8;
            int4 va = *(const int4*)(A + (size_t)(bm + row) * K + k0 + c8);
            *(int4*)&As[row][c8] = va;
            int nrow = bn + row;
            int4 vb = make_int4(0, 0, 0, 0);
            if (nrow < N) vb = *(const int4*)(Bt + (size_t)nrow * K + k0 + c8);
            *(int4*)&Bs[row][c8] = vb;
        }
        __syncthreads();
#pragma unroll
        for (int ks = 0; ks < 64; ks += 32) {
            frag8 af[4], bfr[4];
#pragma unroll
            for (int i = 0; i < 4; ++i)
                af[i] = *(const frag8*)&As[wr*64 + i*16 + m16][ks + quad*8];
#pragma unroll
            for (int j = 0; j < 4; ++j)
                bfr[j] = *(const frag8*)&Bs[wc*64 + j*16 + m16][ks + quad*8];
#pragma unroll
            for (int i = 0; i < 4; ++i)
#pragma unroll
                for (int j = 0; j < 4; ++j)
                    acc[i][j] = __builtin_amdgcn_mfma_f32_16x16x32_bf16(af[i], bfr[j], acc[i][j], 0, 0, 0);
        }
    }

#pragma unroll
    for (int i = 0; i < 4; ++i) {
#pragma unroll
        for (int j = 0; j < 4; ++j) {
            int col = bn + wc*64 + j*16 + m16;
            if (col >= N) continue;
            float bv = bias[col];
#pragma unroll
            for (int r = 0; r < 4; ++r) {
                int row = bm + wr*64 + i*16 + quad*4 + r;
                float v = acc[i][j][r] + bv;
                if constexpr (EPI == 1) v = fmaxf(v, 0.f) + log1pf(expf(-fabsf(v)));
                if constexpr (EPI == 2) v += resid[(size_t)row * N + col];
                Cf[(size_t)row * N + col] = v;
                if constexpr (EPI == 3) {
                    if (col < DTR_) Caux[(size_t)row * DTR_ + col] = f2us(v);
                }
            }
        }
    }
}

// ---------------- depthwise causal conv (K=4) + SiLU -> bf16 -----------------
__global__ __launch_bounds__(256) void conv_silu_kernel(
    const float* __restrict__ proj,
    const float* __restrict__ cw,
    const float* __restrict__ cb,
    us*          __restrict__ x1cb)
{
    int idx = blockIdx.x * 256 + threadIdx.x;   // ROWS*D
    int d   = idx & (D_ - 1);
    int row = idx >> 11;
    int t   = row & (T_ - 1);
    const float* base = proj + (size_t)row * (2*D_) + d;
    float acc = cb[d];
    float w0 = cw[d*4+0], w1 = cw[d*4+1], w2 = cw[d*4+2], w3 = cw[d*4+3];
    acc = fmaf(w3, base[0], acc);
    if (t >= 1) acc = fmaf(w2, base[-(2*D_)],   acc);
    if (t >= 2) acc = fmaf(w1, base[-2*(2*D_)], acc);
    if (t >= 3) acc = fmaf(w0, base[-3*(2*D_)], acc);
    float sg = 1.f / (1.f + expf(-acc));
    x1cb[idx] = f2us(acc * sg);
}

// ------- chunked selective scan + gate, one block per (b,d) channel ----------
__global__ __launch_bounds__(256) void scan_block_kernel(
    const float* __restrict__ delta,
    const us*    __restrict__ x1cb,
    const float* __restrict__ dbc,    // [...,128:144]=Bm [...,144:160]=Cm
    const float* __restrict__ A_log,
    const float* __restrict__ proj,   // g at col D+d
    us*          __restrict__ ybf)    // y*silu(g), bf16
{
    __shared__ float dvs[T_ + NCH];   // swizzle f(t)=t+(t>>6)
    __shared__ float xvs[T_ + NCH];
    __shared__ float gs [T_ + NCH];
    __shared__ float Pl[NCH][N_];
    __shared__ float Sl[NCH][N_];

    const int tid = threadIdx.x;
    const int d = blockIdx.x & (D_ - 1);
    const int b = blockIdx.x >> 11;
    const int n = tid & 15;
    const int c = tid >> 4;
    const size_t rb = (size_t)b * T_;

    for (int i = tid; i < T_; i += 256) {
        int fi = i + (i >> 6);
        dvs[fi] = delta[(rb + i) * D_ + d];
        xvs[fi] = us2f(x1cb[(rb + i) * D_ + d]);
        gs [fi] = proj[(rb + i) * (2*D_) + D_ + d];
    }
    const float a_coef = -expf(A_log[d * N_ + n]);
    __syncthreads();

    float P = 1.f, S = 0.f;
    const int t0 = c * CLEN;
    for (int j = 0; j < CLEN; ++j) {
        int t = t0 + j;
        int ft = t + (t >> 6);
        float dv = dvs[ft];
        float xv = xvs[ft];
        float Bv = dbc[(rb + t) * NDBC + DTR_ + n];
        float a = expf(dv * a_coef);
        P *= a;
        S = fmaf(a, S, dv * Bv * xv);
    }
    Pl[c][n] = P;
    Sl[c][n] = S;
    __syncthreads();

    float h = 0.f;
    for (int c2 = 0; c2 < c; ++c2)
        h = fmaf(Pl[c2][n], h, Sl[c2][n]);

    for (int j = 0; j < CLEN; ++j) {
        int t = t0 + j;
        int ft = t + (t >> 6);
        float dv = dvs[ft];
        float xv = xvs[ft];
        size_t r = rb + t;
        float Bv = dbc[r * NDBC + DTR_ + n];
        float Cv = dbc[r * NDBC + DTR_ + N_ + n];
        float a = expf(dv * a_coef);
        h = fmaf(a, h, dv * Bv * xv);
        float part = h * Cv;
        part += __shfl_xor(part, 1, 16);
        part += __shfl_xor(part, 2, 16);
        part += __shfl_xor(part, 4, 16);
        part += __shfl_xor(part, 8, 16);
        if (n == 0) {
            float g = gs[ft];
            float sg = 1.f / (1.f + expf(-g));
            ybf[r * D_ + d] = f2us(part * g * sg);
        }
    }
}

extern "C" void kernel_launch(void* const* d_in, const int* in_sizes, int n_in,
                              void* d_out, int out_size, void* d_ws, size_t ws_size,
                              hipStream_t stream)
{
    const float* x      = (const float*)d_in[0];
    const float* rms_w  = (const float*)d_in[1];
    const float* in_W   = (const float*)d_in[2];
    const float* in_b   = (const float*)d_in[3];
    const float* conv_w = (const float*)d_in[4];
    const float* conv_b = (const float*)d_in[5];
    const float* A_log  = (const float*)d_in[6];
    const float* dbc_W  = (const float*)d_in[7];
    const float* dbc_b  = (const float*)d_in[8];
    const float* dup_W  = (const float*)d_in[9];
    const float* dup_b  = (const float*)d_in[10];
    const float* out_W  = (const float*)d_in[11];
    const float* out_b  = (const float*)d_in[12];
    float* out = (float*)d_out;

    // ---- workspace layout (86.9 MB; 89.3 MB proven available in R1) ----
    float* ws    = (float*)d_ws;
    float* proj  = ws;                            // 8M f   (x1pre | g)
    float* dbcB  = proj  + (size_t)ROWS*2*D_;     // 327680 f
    float* delta = dbcB  + (size_t)ROWS*NDBC;     // 4M f
    float* scale = delta + (size_t)ROWS*D_;       // 2048 f
    us* hbf   = (us*)(scale + ROWS);              // 2M us
    us* x1cb  = hbf   + (size_t)ROWS*DM_;         // 4M us
    us* dtrb  = x1cb  + (size_t)ROWS*D_;          // 256K us
    us* ybf   = dtrb  + (size_t)ROWS*DTR_;        // 4M us
    us* inWt  = ybf   + (size_t)ROWS*D_;          // 4M us   [4096][1024]
    us* dbcWt = inWt  + (size_t)2*D_*DM_;         // 320K us [160][2048]
    us* dupWt = dbcWt + (size_t)NDBC*D_;          // 256K us [2048][128]
    us* outWt = dupWt + (size_t)D_*DTR_;          // 2M us   [1024][2048]

    dim3 tb(32, 8);
    // weight prep: fp32 [R][C] -> bf16 [C][R]
    transpose_bf<<<dim3(4096/32, 1024/32), tb, 0, stream>>>(in_W,  inWt,  DM_, 2*D_);
    transpose_bf<<<dim3(5,      2048/32), tb, 0, stream>>>(dbc_W, dbcWt, D_,  NDBC);
    transpose_bf<<<dim3(2048/32,      4), tb, 0, stream>>>(dup_W, dupWt, DTR_, D_);
    transpose_bf<<<dim3(1024/32, 2048/32), tb, 0, stream>>>(out_W, outWt, D_,  DM_);

    // rmsnorm -> bf16 A
    rms_scale_kernel<<<ROWS, 256, 0, stream>>>(x, scale);
    hbf_kernel<<<(ROWS*DM_)/256, 256, 0, stream>>>(x, scale, rms_w, hbf);

    // in_proj: proj = h @ in_W + in_b      [2048 x 4096], K=1024
    mgemm<0><<<dim3(4096/128, ROWS/128), 256, 0, stream>>>(
        hbf, inWt, in_b, proj, nullptr, nullptr, ROWS, 2*D_, DM_);

    // conv + silu -> x1c (bf16)
    conv_silu_kernel<<<(ROWS*D_)/256, 256, 0, stream>>>(proj, conv_w, conv_b, x1cb);

    // dbc = x1c @ dbc_W + dbc_b            [2048 x 160], K=2048 (+bf16 aux of cols<128)
    mgemm<3><<<dim3(2, ROWS/128), 256, 0, stream>>>(
        x1cb, dbcWt, dbc_b, dbcB, dtrb, nullptr, ROWS, NDBC, D_);

    // delta = softplus(dtr @ dup_W + dup_b)  [2048 x 2048], K=128
    mgemm<1><<<dim3(2048/128, ROWS/128), 256, 0, stream>>>(
        dtrb, dupWt, dup_b, delta, nullptr, nullptr, ROWS, D_, DTR_);

    // chunked selective scan + gate -> ybf
    scan_block_kernel<<<B_*D_, 256, 0, stream>>>(delta, x1cb, dbcB, A_log, proj, ybf);

    // out = y @ out_W + out_b + residual   [2048 x 1024], K=2048
    mgemm<2><<<dim3(1024/128, ROWS/128), 256, 0, stream>>>(
        ybf, outWt, out_b, out, nullptr, x, ROWS, DM_, D_);
}